// Round 2
// baseline (324.200 us; speedup 1.0000x reference)
//
#include <hip/hip_runtime.h>
#include <math.h>

#define NB 256
#define NV 32000
#define ND 1024
#define NT 64

// ---- GEMM config ----
#define GN 64
#define ASTR 56            // padded row stride (f16) for A lds tile
#define NKB 64             // 1024/16 k-blocks
#define ASLAB (256 * ASTR) // f16 per k-block slab = 14336 (28672 B)
#define NGBLK (NV / GN)    // 500
#define INV2048F 4.8828125e-4f

// ---- sampling config ----
#define NBIN 1024
#define FIX2 4294967296.0   // 2^32
#define PACK1 (1ull << 48)
#define SMASK ((1ull << 48) - 1ull)
#define SMEM_BYTES (NV * 4 + NBIN * 8)  // 128,000 + 8,192 = 136,192 B

typedef _Float16 f16x8 __attribute__((ext_vector_type(8)));
typedef _Float16 f16x4 __attribute__((ext_vector_type(4)));
typedef float f32x16 __attribute__((ext_vector_type(16)));
typedef __attribute__((address_space(3))) void lds_void;
typedef __attribute__((address_space(1))) void glb_void;

struct RowP2 {
  unsigned long long basePack;
  unsigned long long toppZfix;
  unsigned pfx;
  int ktop;
  float invZ;
  unsigned ustar;
  int m;
  int cEq;
};

__device__ __forceinline__ unsigned mono_enc(float f) {
  unsigned u = __float_as_uint(f);
  return (u & 0x80000000u) ? ~u : (u | 0x80000000u);
}
__device__ __forceinline__ float mono_dec(unsigned u) {
  return (u & 0x80000000u) ? __uint_as_float(u & 0x7FFFFFFFu) : __uint_as_float(~u);
}

// ---------------- convert A: LDS-staged slab build, coalesced output ----------------
__global__ __launch_bounds__(256) void convert_A(const float* __restrict__ hidden,
                                                 _Float16* __restrict__ A3) {
  const int kb = blockIdx.x, t = threadIdx.x;
  __shared__ _Float16 slab[ASLAB];  // 28672 B
#pragma unroll
  for (int it = 0; it < 4; it++) {
    const int m = it * 64 + (t >> 2);
    const int k4 = (t & 3) * 4;
    float4 a4 = *(const float4*)(hidden + (size_t)m * ND + kb * 16 + k4);
    _Float16* base = slab + m * ASTR;
    float v[4] = {a4.x, a4.y, a4.z, a4.w};
#pragma unroll
    for (int q = 0; q < 4; q++) {
      const _Float16 h = (_Float16)v[q];
      const _Float16 l2 = (_Float16)((v[q] - (float)h) * 2048.0f);
      const int kk = k4 + q;
      base[kk] = h;
      base[16 + 2 * kk] = h;
      base[17 + 2 * kk] = l2;
    }
  }
  __syncthreads();
  const uint4* s = (const uint4*)slab;
  uint4* g = (uint4*)(A3 + (size_t)kb * ASLAB);
#pragma unroll
  for (int i = 0; i < 7; i++) g[i * 256 + t] = s[i * 256 + t];
}

// ---------------- MFMA f16-split GEMM, software-pipelined (unchanged from R1) -------
__global__ __launch_bounds__(256, 2) void gemm_f16s(
    const float* __restrict__ Bm, const _Float16* __restrict__ A3,
    const float* __restrict__ temp, unsigned* __restrict__ rowmax,
    float* __restrict__ C) {
  __shared__ _Float16 Als[2][ASLAB];      // 57,344 B
  __shared__ _Float16 Bls[2][GN * ASTR];  // 14,336 B
  __shared__ float s_invT[256];
  __shared__ unsigned s_pm[256];

  const int t = threadIdx.x;
  const int l = t & 63, w = t >> 6;
  const int n0 = blockIdx.x * GN;
  s_invT[t] = 1.0f / temp[t];
  s_pm[t] = 0u;

  f32x16 accA[2][2] = {};
  f32x16 accB[2][2] = {};

  const int bn = t >> 2, bk4 = (t & 3) * 4;
  const int l31 = l & 31, lh = l >> 5;
  const int ka = lh * 8;
  const int mb = w * 64;

  const float* browp = Bm + (size_t)(n0 + bn) * ND + bk4;
  const char* gaBase = (const char*)A3 + (w * 7) * 1024 + l * 16;
  char* laB0 = (char*)&Als[0][0] + (w * 7) * 1024;
  char* laB1 = (char*)&Als[1][0] + (w * 7) * 1024;

#define ISSUE_A(kbn, LA)                                                        \
  do {                                                                          \
    const char* ga_ = gaBase + (size_t)(kbn) * (ASLAB * 2);                     \
    _Pragma("unroll") for (int i_ = 0; i_ < 7; i_++)                            \
        __builtin_amdgcn_global_load_lds((const glb_void*)(ga_ + i_ * 1024),    \
                                         (lds_void*)((LA) + i_ * 1024), 16, 0,  \
                                         0);                                    \
  } while (0)

#define BCONV(BV, DST)                                                          \
  do {                                                                          \
    const _Float16 h0_ = (_Float16)(BV).x, h1_ = (_Float16)(BV).y,              \
                   h2_ = (_Float16)(BV).z, h3_ = (_Float16)(BV).w;              \
    const _Float16 q0_ = (_Float16)(((BV).x - (float)h0_) * 2048.0f);           \
    const _Float16 q1_ = (_Float16)(((BV).y - (float)h1_) * 2048.0f);           \
    const _Float16 q2_ = (_Float16)(((BV).z - (float)h2_) * 2048.0f);           \
    const _Float16 q3_ = (_Float16)(((BV).w - (float)h3_) * 2048.0f);           \
    _Float16* prow_ = (DST) + bn * ASTR;                                        \
    *(f16x4*)(prow_ + bk4) = (f16x4){h0_, h1_, h2_, h3_};                       \
    *(f16x8*)(prow_ + 16 + 2 * bk4) =                                           \
        (f16x8){q0_, h0_, q1_, h1_, q2_, h2_, q3_, h3_};                        \
  } while (0)

#define COMPUTE(CUR)                                                                       \
  do {                                                                                     \
    const _Float16* Ap_ = &Als[CUR][0] + (size_t)(mb + l31) * ASTR + ka;                   \
    const _Float16* Bp_ = &Bls[CUR][0] + (size_t)l31 * ASTR + ka;                          \
    f16x8 a0_ = *(const f16x8*)(Ap_);                                                      \
    f16x8 a1_ = *(const f16x8*)(Ap_ + 32 * ASTR);                                          \
    f16x8 b0_ = *(const f16x8*)(Bp_);                                                      \
    f16x8 b1_ = *(const f16x8*)(Bp_ + 32 * ASTR);                                          \
    accA[0][0] = __builtin_amdgcn_mfma_f32_32x32x16_f16(a0_, b0_, accA[0][0], 0, 0, 0);    \
    accA[0][1] = __builtin_amdgcn_mfma_f32_32x32x16_f16(a0_, b1_, accA[0][1], 0, 0, 0);    \
    accA[1][0] = __builtin_amdgcn_mfma_f32_32x32x16_f16(a1_, b0_, accA[1][0], 0, 0, 0);    \
    accA[1][1] = __builtin_amdgcn_mfma_f32_32x32x16_f16(a1_, b1_, accA[1][1], 0, 0, 0);    \
    _Pragma("unroll") for (int s_ = 0; s_ < 2; s_++) {                                     \
      const int off_ = 16 + s_ * 16;                                                       \
      f16x8 c0_ = *(const f16x8*)(Ap_ + off_);                                             \
      f16x8 c1_ = *(const f16x8*)(Ap_ + 32 * ASTR + off_);                                 \
      f16x8 d0_ = *(const f16x8*)(Bp_ + off_);                                             \
      f16x8 d1_ = *(const f16x8*)(Bp_ + 32 * ASTR + off_);                                 \
      accB[0][0] = __builtin_amdgcn_mfma_f32_32x32x16_f16(c0_, d0_, accB[0][0], 0, 0, 0);  \
      accB[0][1] = __builtin_amdgcn_mfma_f32_32x32x16_f16(c0_, d1_, accB[0][1], 0, 0, 0);  \
      accB[1][0] = __builtin_amdgcn_mfma_f32_32x32x16_f16(c1_, d0_, accB[1][0], 0, 0, 0);  \
      accB[1][1] = __builtin_amdgcn_mfma_f32_32x32x16_f16(c1_, d1_, accB[1][1], 0, 0, 0);  \
    }                                                                                      \
  } while (0)

  ISSUE_A(0, laB0);
  __builtin_amdgcn_sched_barrier(0);
  float4 bv0 = *(const float4*)(browp);
  __builtin_amdgcn_sched_barrier(0);
  float4 bvA = *(const float4*)(browp + 16);  // B[1]
  __builtin_amdgcn_sched_barrier(0);
  asm volatile("s_waitcnt vmcnt(1)" ::: "memory");
  BCONV(bv0, &Bls[0][0]);
  asm volatile("s_waitcnt lgkmcnt(0)\ns_barrier" ::: "memory");

  float4 bvB;
  for (int kb = 0; kb < 62; kb += 2) {
    ISSUE_A(kb + 1, laB1);
    __builtin_amdgcn_sched_barrier(0);
    bvB = *(const float4*)(browp + (size_t)(kb + 2) * 16);
    __builtin_amdgcn_sched_barrier(0);
    asm volatile("s_waitcnt vmcnt(9)" ::: "memory");
    COMPUTE(0);
    __builtin_amdgcn_sched_barrier(0);
    asm volatile("s_waitcnt vmcnt(8)" ::: "memory");
    BCONV(bvA, &Bls[1][0]);
    asm volatile("s_waitcnt lgkmcnt(0)\ns_barrier" ::: "memory");

    ISSUE_A(kb + 2, laB0);
    __builtin_amdgcn_sched_barrier(0);
    bvA = *(const float4*)(browp + (size_t)(kb + 3) * 16);
    __builtin_amdgcn_sched_barrier(0);
    asm volatile("s_waitcnt vmcnt(9)" ::: "memory");
    COMPUTE(1);
    __builtin_amdgcn_sched_barrier(0);
    asm volatile("s_waitcnt vmcnt(8)" ::: "memory");
    BCONV(bvB, &Bls[0][0]);
    asm volatile("s_waitcnt lgkmcnt(0)\ns_barrier" ::: "memory");
  }

  ISSUE_A(63, laB1);
  __builtin_amdgcn_sched_barrier(0);
  asm volatile("s_waitcnt vmcnt(8)" ::: "memory");
  COMPUTE(0);
  __builtin_amdgcn_sched_barrier(0);
  asm volatile("s_waitcnt vmcnt(7)" ::: "memory");
  BCONV(bvA, &Bls[1][0]);
  asm volatile("s_waitcnt lgkmcnt(0)\ns_barrier" ::: "memory");

  asm volatile("s_waitcnt vmcnt(0)" ::: "memory");
  COMPUTE(1);

#undef ISSUE_A
#undef BCONV
#undef COMPUTE

#pragma unroll
  for (int mi = 0; mi < 2; mi++) {
#pragma unroll
    for (int r = 0; r < 16; r++) {
      const int row = mb + mi * 32 + (r & 3) + 8 * (r >> 2) + 4 * lh;
      const float it = s_invT[row];
      float v0 = (accA[mi][0][r] + accB[mi][0][r] * INV2048F) * it;
      float v1 = (accA[mi][1][r] + accB[mi][1][r] * INV2048F) * it;
      C[(size_t)row * NV + n0 + l31] = v0;
      C[(size_t)row * NV + n0 + 32 + l31] = v1;
      float mx = fmaxf(v0, v1);
#pragma unroll
      for (int o = 1; o < 32; o <<= 1) mx = fmaxf(mx, __shfl_xor(mx, o));
      if (l31 == 0) atomicMax(&s_pm[row], mono_enc(mx));
    }
  }
  __syncthreads();
  atomicMax(&rowmax[t], s_pm[t]);
}

// ---------------- fused per-row sampler: penalties + exp + 3-level radix-select
//                  + filter + tie-rank, entirely block-local (row in 128 KB LDS) ----
__global__ __launch_bounds__(256) void sample_row(
    float* __restrict__ buf, const unsigned* __restrict__ rowmax,
    const int* __restrict__ toks, const float* __restrict__ pres,
    const float* __restrict__ freq, const float* __restrict__ temp,
    const float* __restrict__ topp_a, const int* __restrict__ topk_a) {
  extern __shared__ char smem[];
  float* e = (float*)smem;                                        // 32000 f32
  unsigned long long* h = (unsigned long long*)(smem + NV * 4);   // 1024 u64 (hist, reused as suffix)
  __shared__ unsigned long long sc[256];
  __shared__ int s_rank[256];
  __shared__ int s_tok[NT];
  __shared__ int s_bs;
  __shared__ RowP2 sp;

  const int b = blockIdx.x, t = threadIdx.x;
  float* row = buf + (size_t)b * NV;

  // ---- load row into LDS, zero hist ----
  if (t < NT) s_tok[t] = toks[b * NT + t];
  for (int i = t; i < NBIN; i += 256) h[i] = 0ull;
  for (int i4 = t; i4 < NV / 4; i4 += 256)
    *(float4*)(e + i4 * 4) = *(const float4*)(row + i4 * 4);
  __syncthreads();

  // ---- penalties (row holds logits/temp; subtract pen/temp) ----
  if (t < NT) {
    const int tk = s_tok[t];
    bool first = true; int cnt = 0;
    for (int j = 0; j < NT; j++)
      if (s_tok[j] == tk) { if (j < t) first = false; cnt++; }
    if (first) e[tk] -= (freq[b] * (float)cnt + pres[b]) / temp[b];
  }
  __syncthreads();

  // ---- exp in place + level-0 histogram ----
  const float M = mono_dec(rowmax[b]);
  for (int i4 = t; i4 < NV / 4; i4 += 256) {
    float4 x4 = *(const float4*)(e + i4 * 4);
    float4 e4;
    e4.x = expf(x4.x - M); e4.y = expf(x4.y - M);
    e4.z = expf(x4.z - M); e4.w = expf(x4.w - M);
    *(float4*)(e + i4 * 4) = e4;
    unsigned k;
    k = __float_as_uint(e4.x); if (k) atomicAdd(&h[k >> 20], PACK1 | (unsigned long long)(e4.x * FIX2));
    k = __float_as_uint(e4.y); if (k) atomicAdd(&h[k >> 20], PACK1 | (unsigned long long)(e4.y * FIX2));
    k = __float_as_uint(e4.z); if (k) atomicAdd(&h[k >> 20], PACK1 | (unsigned long long)(e4.z * FIX2));
    k = __float_as_uint(e4.w); if (k) atomicAdd(&h[k >> 20], PACK1 | (unsigned long long)(e4.w * FIX2));
  }
  __syncthreads();

  // ---- 3-level radix descent, all block-local ----
  for (int level = 0; level < 3; level++) {
    unsigned long long v0 = h[t * 4], v1 = h[t * 4 + 1],
                       v2 = h[t * 4 + 2], v3 = h[t * 4 + 3];
    if (t == 0) s_bs = 1023;
    sc[t] = v0 + v1 + v2 + v3;
    __syncthreads();
    for (int off = 1; off < 256; off <<= 1) {
      unsigned long long add = (t + off < 256) ? sc[t + off] : 0ull;
      __syncthreads();
      sc[t] += add;
      __syncthreads();
    }
    const unsigned long long totalP = sc[0];
    unsigned long long run = (t < 255) ? sc[t + 1] : 0ull;
    // reuse h as the suffix array (each thread only rewrites its own 4 bins)
    h[t * 4 + 3] = run; run += v3;
    h[t * 4 + 2] = run; run += v2;
    h[t * 4 + 1] = run; run += v1;
    h[t * 4 + 0] = run;
    __syncthreads();

    unsigned long long base, toppZ;
    int ktop_;
    if (level == 0) {
      ktop_ = topk_a[b];
      unsigned long long Zfix = totalP & SMASK;
      if (!Zfix) Zfix = 1ull;
      toppZ = (unsigned long long)((double)topp_a[b] * (double)Zfix);
      base = 0ull;
    } else {
      base = sp.basePack; toppZ = sp.toppZfix; ktop_ = sp.ktop;
    }

#pragma unroll
    for (int i = 0; i < 4; i++) {
      const int bin = t * 4 + i;
      const unsigned long long sG = base + h[bin];
      const bool A = ((long long)(sG >> 48) < (long long)ktop_) && ((sG & SMASK) <= toppZ);
      const unsigned long long sPfull = base + ((bin > 0) ? h[bin - 1] : totalP);
      const bool Ap = ((long long)(sPfull >> 48) < (long long)ktop_) && ((sPfull & SMASK) <= toppZ);
      if (A && !Ap) s_bs = bin;
    }
    __syncthreads();
    if (t == 0) {
      const int bs = s_bs;
      const unsigned long long newBase = base + h[bs];
      if (level == 0) {
        unsigned long long Zfix = totalP & SMASK;
        if (!Zfix) Zfix = 1ull;
        sp.invZ = (float)(FIX2 / (double)Zfix);
      }
      if (level < 2) {
        sp.basePack = newBase;
        sp.toppZfix = toppZ;
        sp.ktop = ktop_;
        sp.pfx = (level == 0) ? (unsigned)bs : ((sp.pfx << 10) | (unsigned)bs);
      } else {
        const unsigned ustar = (sp.pfx << 10) | (unsigned)bs;
        const unsigned long long raw = ((bs > 0) ? h[bs - 1] : totalP) - h[bs];
        const int cEq = (int)(raw >> 48);
        const long long Chi = (long long)(newBase >> 48);
        const unsigned long long Shi = newBase & SMASK;
        long long m = cEq;
        const long long lim = (long long)ktop_ - Chi;
        if (lim < m) m = lim;
        const double tf = (double)__uint_as_float(ustar) * FIX2;
        const double rem = (double)(toppZ - Shi);
        const double Rd = floor(rem / tf) + 1.0;
        if (Rd < (double)m) m = (long long)Rd;
        if (m < 1) m = 1;
        sp.ustar = ustar; sp.m = (int)m; sp.cEq = cEq;
      }
    }
    __syncthreads();
    if (level < 2) {
      for (int i = t; i < NBIN; i += 256) h[i] = 0ull;
      __syncthreads();
      const unsigned pfx = sp.pfx;
      const int ms = (level == 0) ? 20 : 10;
      const int bsh = (level == 0) ? 10 : 0;
      for (int i4 = t; i4 < NV / 4; i4 += 256) {
        float4 e4 = *(const float4*)(e + i4 * 4);
        unsigned k;
        k = __float_as_uint(e4.x); if (k && (k >> ms) == pfx) atomicAdd(&h[(k >> bsh) & 1023u], PACK1 | (unsigned long long)(e4.x * FIX2));
        k = __float_as_uint(e4.y); if (k && (k >> ms) == pfx) atomicAdd(&h[(k >> bsh) & 1023u], PACK1 | (unsigned long long)(e4.y * FIX2));
        k = __float_as_uint(e4.z); if (k && (k >> ms) == pfx) atomicAdd(&h[(k >> bsh) & 1023u], PACK1 | (unsigned long long)(e4.z * FIX2));
        k = __float_as_uint(e4.w); if (k && (k >> ms) == pfx) atomicAdd(&h[(k >> bsh) & 1023u], PACK1 | (unsigned long long)(e4.w * FIX2));
      }
      __syncthreads();
    }
  }

  // ---- final filter ----
  const unsigned ustar = sp.ustar;
  const float invZ = sp.invZ;
  if (sp.m >= sp.cEq) {
    // all ties kept: k >= ustar survives (k==0 case writes 0 either way)
    for (int i4 = t; i4 < NV / 4; i4 += 256) {
      float4 e4 = *(const float4*)(e + i4 * 4);
      float4 o4;
      unsigned k;
      k = __float_as_uint(e4.x); o4.x = (k >= ustar) ? e4.x * invZ : 0.f;
      k = __float_as_uint(e4.y); o4.y = (k >= ustar) ? e4.y * invZ : 0.f;
      k = __float_as_uint(e4.z); o4.z = (k >= ustar) ? e4.z * invZ : 0.f;
      k = __float_as_uint(e4.w); o4.w = (k >= ustar) ? e4.w * invZ : 0.f;
      *(float4*)(row + i4 * 4) = o4;
    }
  } else {
    // rare: rank ties by vocab index, keep first m (contiguous chunks for index order)
    const int m = sp.m;
    const int CH = NV / 256;  // 125
    const int base0 = t * CH;
    int myc = 0;
    for (int v = base0; v < base0 + CH; v++)
      myc += (__float_as_uint(e[v]) == ustar);
    s_rank[t] = myc;
    __syncthreads();
    for (int off = 1; off < 256; off <<= 1) {
      const int a0 = s_rank[t];
      const int an = (t >= off) ? s_rank[t - off] : 0;
      __syncthreads();
      s_rank[t] = a0 + an;
      __syncthreads();
    }
    int r = (t > 0) ? s_rank[t - 1] : 0;
    for (int v = base0; v < base0 + CH; v++) {
      const unsigned k = __float_as_uint(e[v]);
      float o = (k > ustar) ? e[v] * invZ : 0.f;
      if (k == ustar) { o = (r < m) ? e[v] * invZ : 0.f; r++; }
      row[v] = o;
    }
  }
}

extern "C" void kernel_launch(void* const* d_in, const int* in_sizes, int n_in,
                              void* d_out, int out_size, void* d_ws, size_t ws_size,
                              hipStream_t stream) {
  (void)in_sizes; (void)n_in; (void)out_size; (void)ws_size;
  const float* hidden = (const float*)d_in[0];
  const float* emb    = (const float*)d_in[1];
  const int*   toks   = (const int*)d_in[2];
  const float* pres   = (const float*)d_in[3];
  const float* freq   = (const float*)d_in[4];
  const float* temp   = (const float*)d_in[5];
  const float* topp   = (const float*)d_in[6];
  const int*   topk   = (const int*)d_in[7];
  float* out = (float*)d_out;

  // ws layout: A3 (1,835,008 B) + rowmax (1,024 B, zeroed)
  const size_t offA3 = 0;
  const size_t offRM = 1835008;

  _Float16* A3 = (_Float16*)((char*)d_ws + offA3);
  unsigned* rowmax = (unsigned*)((char*)d_ws + offRM);

  // opt-in for >64KB dynamic LDS (cheap, idempotent, capture-safe host-side call)
  hipFuncSetAttribute((const void*)sample_row,
                      hipFuncAttributeMaxDynamicSharedMemorySize, SMEM_BYTES);

  hipMemsetAsync((char*)d_ws + offRM, 0, 1024, stream);
  convert_A<<<NKB, 256, 0, stream>>>(hidden, A3);
  gemm_f16s<<<NGBLK, 256, 0, stream>>>(emb, A3, temp, rowmax, out);
  sample_row<<<NB, 256, SMEM_BYTES, stream>>>(out, rowmax, toks, pres, freq,
                                              temp, topp, topk);
}

// Round 3
// 299.952 us; speedup vs baseline: 1.0808x; 1.0808x over previous
//
#include <hip/hip_runtime.h>
#include <math.h>

#define NB 256
#define NV 32000
#define ND 1024
#define NT 64

// ---- GEMM config ----
#define GN 64
#define ASTR 56            // padded row stride (f16) for A lds tile
#define NKB 64             // 1024/16 k-blocks
#define ASLAB (256 * ASTR) // f16 per k-block slab = 14336 (28672 B)
#define NGBLK (NV / GN)    // 500
#define INV2048F 4.8828125e-4f

// ---- sampling config ----
#define NBIN 1024
#define HSTR 1032                       // padded copy stride (u32) to decorrelate banks
#define HTOT (4 * HSTR)                 // lo0|lo1|hc0|hc1 = 4128 u32
#define FIX2 4294967296.0   // 2^32
#define SMASK ((1ull << 48) - 1ull)
#define SMEM_BYTES (NV * 4 + HTOT * 4)  // 128000 + 16512 = 144512 B

typedef _Float16 f16x8 __attribute__((ext_vector_type(8)));
typedef _Float16 f16x4 __attribute__((ext_vector_type(4)));
typedef float f32x16 __attribute__((ext_vector_type(16)));
typedef __attribute__((address_space(3))) void lds_void;
typedef __attribute__((address_space(1))) void glb_void;

struct RowP2 {
  unsigned long long basePack;
  unsigned long long toppZfix;
  unsigned pfx;
  int ktop;
  float invZ;
  unsigned ustar;
  int m;
  int cEq;
};

__device__ __forceinline__ unsigned mono_enc(float f) {
  unsigned u = __float_as_uint(f);
  return (u & 0x80000000u) ? ~u : (u | 0x80000000u);
}
__device__ __forceinline__ float mono_dec(unsigned u) {
  return (u & 0x80000000u) ? __uint_as_float(u & 0x7FFFFFFFu) : __uint_as_float(~u);
}

// ---------------- convert A: LDS-staged slab build, coalesced output ----------------
__global__ __launch_bounds__(256) void convert_A(const float* __restrict__ hidden,
                                                 _Float16* __restrict__ A3) {
  const int kb = blockIdx.x, t = threadIdx.x;
  __shared__ _Float16 slab[ASLAB];  // 28672 B
#pragma unroll
  for (int it = 0; it < 4; it++) {
    const int m = it * 64 + (t >> 2);
    const int k4 = (t & 3) * 4;
    float4 a4 = *(const float4*)(hidden + (size_t)m * ND + kb * 16 + k4);
    _Float16* base = slab + m * ASTR;
    float v[4] = {a4.x, a4.y, a4.z, a4.w};
#pragma unroll
    for (int q = 0; q < 4; q++) {
      const _Float16 h = (_Float16)v[q];
      const _Float16 l2 = (_Float16)((v[q] - (float)h) * 2048.0f);
      const int kk = k4 + q;
      base[kk] = h;
      base[16 + 2 * kk] = h;
      base[17 + 2 * kk] = l2;
    }
  }
  __syncthreads();
  const uint4* s = (const uint4*)slab;
  uint4* g = (uint4*)(A3 + (size_t)kb * ASLAB);
#pragma unroll
  for (int i = 0; i < 7; i++) g[i * 256 + t] = s[i * 256 + t];
}

// ---------------- MFMA f16-split GEMM, software-pipelined (unchanged) ----------------
__global__ __launch_bounds__(256, 2) void gemm_f16s(
    const float* __restrict__ Bm, const _Float16* __restrict__ A3,
    const float* __restrict__ temp, unsigned* __restrict__ rowmax,
    float* __restrict__ C) {
  __shared__ _Float16 Als[2][ASLAB];      // 57,344 B
  __shared__ _Float16 Bls[2][GN * ASTR];  // 14,336 B
  __shared__ float s_invT[256];
  __shared__ unsigned s_pm[256];

  const int t = threadIdx.x;
  const int l = t & 63, w = t >> 6;
  const int n0 = blockIdx.x * GN;
  s_invT[t] = 1.0f / temp[t];
  s_pm[t] = 0u;

  f32x16 accA[2][2] = {};
  f32x16 accB[2][2] = {};

  const int bn = t >> 2, bk4 = (t & 3) * 4;
  const int l31 = l & 31, lh = l >> 5;
  const int ka = lh * 8;
  const int mb = w * 64;

  const float* browp = Bm + (size_t)(n0 + bn) * ND + bk4;
  const char* gaBase = (const char*)A3 + (w * 7) * 1024 + l * 16;
  char* laB0 = (char*)&Als[0][0] + (w * 7) * 1024;
  char* laB1 = (char*)&Als[1][0] + (w * 7) * 1024;

#define ISSUE_A(kbn, LA)                                                        \
  do {                                                                          \
    const char* ga_ = gaBase + (size_t)(kbn) * (ASLAB * 2);                     \
    _Pragma("unroll") for (int i_ = 0; i_ < 7; i_++)                            \
        __builtin_amdgcn_global_load_lds((const glb_void*)(ga_ + i_ * 1024),    \
                                         (lds_void*)((LA) + i_ * 1024), 16, 0,  \
                                         0);                                    \
  } while (0)

#define BCONV(BV, DST)                                                          \
  do {                                                                          \
    const _Float16 h0_ = (_Float16)(BV).x, h1_ = (_Float16)(BV).y,              \
                   h2_ = (_Float16)(BV).z, h3_ = (_Float16)(BV).w;              \
    const _Float16 q0_ = (_Float16)(((BV).x - (float)h0_) * 2048.0f);           \
    const _Float16 q1_ = (_Float16)(((BV).y - (float)h1_) * 2048.0f);           \
    const _Float16 q2_ = (_Float16)(((BV).z - (float)h2_) * 2048.0f);           \
    const _Float16 q3_ = (_Float16)(((BV).w - (float)h3_) * 2048.0f);           \
    _Float16* prow_ = (DST) + bn * ASTR;                                        \
    *(f16x4*)(prow_ + bk4) = (f16x4){h0_, h1_, h2_, h3_};                       \
    *(f16x8*)(prow_ + 16 + 2 * bk4) =                                           \
        (f16x8){q0_, h0_, q1_, h1_, q2_, h2_, q3_, h3_};                        \
  } while (0)

#define COMPUTE(CUR)                                                                       \
  do {                                                                                     \
    const _Float16* Ap_ = &Als[CUR][0] + (size_t)(mb + l31) * ASTR + ka;                   \
    const _Float16* Bp_ = &Bls[CUR][0] + (size_t)l31 * ASTR + ka;                          \
    f16x8 a0_ = *(const f16x8*)(Ap_);                                                      \
    f16x8 a1_ = *(const f16x8*)(Ap_ + 32 * ASTR);                                          \
    f16x8 b0_ = *(const f16x8*)(Bp_);                                                      \
    f16x8 b1_ = *(const f16x8*)(Bp_ + 32 * ASTR);                                          \
    accA[0][0] = __builtin_amdgcn_mfma_f32_32x32x16_f16(a0_, b0_, accA[0][0], 0, 0, 0);    \
    accA[0][1] = __builtin_amdgcn_mfma_f32_32x32x16_f16(a0_, b1_, accA[0][1], 0, 0, 0);    \
    accA[1][0] = __builtin_amdgcn_mfma_f32_32x32x16_f16(a1_, b0_, accA[1][0], 0, 0, 0);    \
    accA[1][1] = __builtin_amdgcn_mfma_f32_32x32x16_f16(a1_, b1_, accA[1][1], 0, 0, 0);    \
    _Pragma("unroll") for (int s_ = 0; s_ < 2; s_++) {                                     \
      const int off_ = 16 + s_ * 16;                                                       \
      f16x8 c0_ = *(const f16x8*)(Ap_ + off_);                                             \
      f16x8 c1_ = *(const f16x8*)(Ap_ + 32 * ASTR + off_);                                 \
      f16x8 d0_ = *(const f16x8*)(Bp_ + off_);                                             \
      f16x8 d1_ = *(const f16x8*)(Bp_ + 32 * ASTR + off_);                                 \
      accB[0][0] = __builtin_amdgcn_mfma_f32_32x32x16_f16(c0_, d0_, accB[0][0], 0, 0, 0);  \
      accB[0][1] = __builtin_amdgcn_mfma_f32_32x32x16_f16(c0_, d1_, accB[0][1], 0, 0, 0);  \
      accB[1][0] = __builtin_amdgcn_mfma_f32_32x32x16_f16(c1_, d0_, accB[1][0], 0, 0, 0);  \
      accB[1][1] = __builtin_amdgcn_mfma_f32_32x32x16_f16(c1_, d1_, accB[1][1], 0, 0, 0);  \
    }                                                                                      \
  } while (0)

  ISSUE_A(0, laB0);
  __builtin_amdgcn_sched_barrier(0);
  float4 bv0 = *(const float4*)(browp);
  __builtin_amdgcn_sched_barrier(0);
  float4 bvA = *(const float4*)(browp + 16);  // B[1]
  __builtin_amdgcn_sched_barrier(0);
  asm volatile("s_waitcnt vmcnt(1)" ::: "memory");
  BCONV(bv0, &Bls[0][0]);
  asm volatile("s_waitcnt lgkmcnt(0)\ns_barrier" ::: "memory");

  float4 bvB;
  for (int kb = 0; kb < 62; kb += 2) {
    ISSUE_A(kb + 1, laB1);
    __builtin_amdgcn_sched_barrier(0);
    bvB = *(const float4*)(browp + (size_t)(kb + 2) * 16);
    __builtin_amdgcn_sched_barrier(0);
    asm volatile("s_waitcnt vmcnt(9)" ::: "memory");
    COMPUTE(0);
    __builtin_amdgcn_sched_barrier(0);
    asm volatile("s_waitcnt vmcnt(8)" ::: "memory");
    BCONV(bvA, &Bls[1][0]);
    asm volatile("s_waitcnt lgkmcnt(0)\ns_barrier" ::: "memory");

    ISSUE_A(kb + 2, laB0);
    __builtin_amdgcn_sched_barrier(0);
    bvA = *(const float4*)(browp + (size_t)(kb + 3) * 16);
    __builtin_amdgcn_sched_barrier(0);
    asm volatile("s_waitcnt vmcnt(9)" ::: "memory");
    COMPUTE(1);
    __builtin_amdgcn_sched_barrier(0);
    asm volatile("s_waitcnt vmcnt(8)" ::: "memory");
    BCONV(bvB, &Bls[0][0]);
    asm volatile("s_waitcnt lgkmcnt(0)\ns_barrier" ::: "memory");
  }

  ISSUE_A(63, laB1);
  __builtin_amdgcn_sched_barrier(0);
  asm volatile("s_waitcnt vmcnt(8)" ::: "memory");
  COMPUTE(0);
  __builtin_amdgcn_sched_barrier(0);
  asm volatile("s_waitcnt vmcnt(7)" ::: "memory");
  BCONV(bvA, &Bls[1][0]);
  asm volatile("s_waitcnt lgkmcnt(0)\ns_barrier" ::: "memory");

  asm volatile("s_waitcnt vmcnt(0)" ::: "memory");
  COMPUTE(1);

#undef ISSUE_A
#undef BCONV
#undef COMPUTE

#pragma unroll
  for (int mi = 0; mi < 2; mi++) {
#pragma unroll
    for (int r = 0; r < 16; r++) {
      const int row = mb + mi * 32 + (r & 3) + 8 * (r >> 2) + 4 * lh;
      const float it = s_invT[row];
      float v0 = (accA[mi][0][r] + accB[mi][0][r] * INV2048F) * it;
      float v1 = (accA[mi][1][r] + accB[mi][1][r] * INV2048F) * it;
      C[(size_t)row * NV + n0 + l31] = v0;
      C[(size_t)row * NV + n0 + 32 + l31] = v1;
      float mx = fmaxf(v0, v1);
#pragma unroll
      for (int o = 1; o < 32; o <<= 1) mx = fmaxf(mx, __shfl_xor(mx, o));
      if (l31 == 0) atomicMax(&s_pm[row], mono_enc(mx));
    }
  }
  __syncthreads();
  atomicMax(&rowmax[t], s_pm[t]);
}

// ---------------- fused per-row sampler, 1024 threads, u32-atomic histograms --------
// LDS: e[32000] f32 (row) | hist: lo0|lo1|hc0|hc1 (stride HSTR u32 each).
//   lo  = wrapped low-32 fixed-point sum (ds_add_rtn_u32, carry via old+x<x)
//   hc  = (count<<16) | (hi-part+carries)   -- one u32 atomic, no overflow possible
// Wave-parity privatization (cp = (t>>6)&1) halves same-address serialization.
// Suffix-scan buffer (u64[1024]) aliases lo0|lo1 (dead between reduce and re-zero).
__global__ __launch_bounds__(1024) void sample_row(
    float* __restrict__ buf, const unsigned* __restrict__ rowmax,
    const int* __restrict__ toks, const float* __restrict__ pres,
    const float* __restrict__ freq, const float* __restrict__ temp,
    const float* __restrict__ topp_a, const int* __restrict__ topk_a) {
  extern __shared__ char smem[];
  float* e = (float*)smem;                               // 32000 f32
  unsigned* hist = (unsigned*)(smem + NV * 4);           // HTOT u32
  unsigned long long* suf = (unsigned long long*)hist;   // 1024 u64, aliases lo0|lo1
  __shared__ int s_tok[NT];
  __shared__ int s_bs;
  __shared__ RowP2 sp;

  const int b = blockIdx.x, t = threadIdx.x;
  const int cp = (t >> 6) & 1;
  unsigned* loP = hist + cp * HSTR;
  unsigned* hcP = hist + 2 * HSTR + cp * HSTR;
  float* row = buf + (size_t)b * NV;

#define HACC(EV, BIN)                                                    \
  do {                                                                   \
    unsigned long long f_ = (unsigned long long)((double)(EV) * FIX2);   \
    unsigned flo_ = (unsigned)f_;                                        \
    unsigned old_ = atomicAdd(&loP[BIN], flo_);                          \
    unsigned hc_ = 0x10000u + (unsigned)(f_ >> 32) +                     \
                   ((old_ + flo_ < flo_) ? 1u : 0u);                     \
    atomicAdd(&hcP[BIN], hc_);                                           \
  } while (0)

  // ---- load row into LDS, zero hist ----
  if (t < NT) s_tok[t] = toks[b * NT + t];
  for (int i = t; i < HTOT; i += 1024) hist[i] = 0u;
  for (int i4 = t; i4 < NV / 4; i4 += 1024)
    *(float4*)(e + i4 * 4) = *(const float4*)(row + i4 * 4);
  __syncthreads();

  // ---- penalties ----
  if (t < NT) {
    const int tk = s_tok[t];
    bool first = true; int cnt = 0;
    for (int j = 0; j < NT; j++)
      if (s_tok[j] == tk) { if (j < t) first = false; cnt++; }
    if (first) e[tk] -= (freq[b] * (float)cnt + pres[b]) / temp[b];
  }
  __syncthreads();

  // ---- pass 0: exp in place + level-0 histogram (bin = k>>20) ----
  const float M = mono_dec(rowmax[b]);
  for (int i4 = t; i4 < NV / 4; i4 += 1024) {
    float4 x4 = *(const float4*)(e + i4 * 4);
    float4 e4;
    e4.x = expf(x4.x - M); e4.y = expf(x4.y - M);
    e4.z = expf(x4.z - M); e4.w = expf(x4.w - M);
    *(float4*)(e + i4 * 4) = e4;
    unsigned k;
    k = __float_as_uint(e4.x); if (k) HACC(e4.x, k >> 20);
    k = __float_as_uint(e4.y); if (k) HACC(e4.y, k >> 20);
    k = __float_as_uint(e4.z); if (k) HACC(e4.z, k >> 20);
    k = __float_as_uint(e4.w); if (k) HACC(e4.w, k >> 20);
  }
  __syncthreads();

  // ---- 3-level radix descent ----
  for (int level = 0; level < 3; level++) {
    // reduce 2 copies -> packed u64 per bin (thread t owns bin t)
    const unsigned lo0 = hist[t], lo1 = hist[HSTR + t];
    const unsigned hc0 = hist[2 * HSTR + t], hc1 = hist[3 * HSTR + t];
    const unsigned c = (hc0 >> 16) + (hc1 >> 16);
    const unsigned long long sum =
        (((unsigned long long)((hc0 & 0xFFFFu) + (hc1 & 0xFFFFu))) << 32) +
        (unsigned long long)lo0 + (unsigned long long)lo1;
    const unsigned long long v = ((unsigned long long)c << 48) + sum;
    __syncthreads();          // reads done before suf overwrites lo regions
    suf[t] = v;
    __syncthreads();
    for (int off = 1; off < NBIN; off <<= 1) {
      unsigned long long add = (t + off < NBIN) ? suf[t + off] : 0ull;
      __syncthreads();
      suf[t] += add;
      __syncthreads();
    }
    const unsigned long long totalP = suf[0];
    if (t == 0) s_bs = NBIN - 1;
    __syncthreads();

    unsigned long long base, toppZ;
    int ktop_;
    if (level == 0) {
      ktop_ = topk_a[b];
      unsigned long long Zfix = totalP & SMASK;
      if (!Zfix) Zfix = 1ull;
      toppZ = (unsigned long long)((double)topp_a[b] * (double)Zfix);
      base = 0ull;
    } else {
      base = sp.basePack; toppZ = sp.toppZfix; ktop_ = sp.ktop;
    }

    {
      const unsigned long long sG = base + suf[t];
      const bool A = ((long long)(sG >> 48) < (long long)ktop_) && ((sG & SMASK) <= toppZ);
      const unsigned long long sP = base + ((t > 0) ? suf[t - 1] : totalP);
      const bool Ap = ((long long)(sP >> 48) < (long long)ktop_) && ((sP & SMASK) <= toppZ);
      if (A && !Ap) s_bs = t;
    }
    __syncthreads();
    if (t == 0) {
      const int bs = s_bs;
      const unsigned long long newBase = base + suf[bs];
      if (level == 0) {
        unsigned long long Zfix = totalP & SMASK;
        if (!Zfix) Zfix = 1ull;
        sp.invZ = (float)(FIX2 / (double)Zfix);
      }
      if (level < 2) {
        sp.basePack = newBase;
        sp.toppZfix = toppZ;
        sp.ktop = ktop_;
        sp.pfx = (level == 0) ? (unsigned)bs : ((sp.pfx << 10) | (unsigned)bs);
      } else {
        const unsigned ustar = (sp.pfx << 10) | (unsigned)bs;
        const unsigned long long raw = ((bs > 0) ? suf[bs - 1] : totalP) - suf[bs];
        const int cEq = (int)(raw >> 48);
        const long long Chi = (long long)(newBase >> 48);
        const unsigned long long Shi = newBase & SMASK;
        long long m = cEq;
        const long long lim = (long long)ktop_ - Chi;
        if (lim < m) m = lim;
        const double tf = (double)__uint_as_float(ustar) * FIX2;
        const double rem = (double)(toppZ - Shi);
        const double Rd = floor(rem / tf) + 1.0;
        if (Rd < (double)m) m = (long long)Rd;
        if (m < 1) m = 1;
        sp.ustar = ustar; sp.m = (int)m; sp.cEq = cEq;
      }
    }
    __syncthreads();

    if (level < 2) {
      for (int i = t; i < HTOT; i += 1024) hist[i] = 0u;
      __syncthreads();
      const unsigned pfx = sp.pfx;
      const int ms = (level == 0) ? 20 : 10;
      const int bsh = (level == 0) ? 10 : 0;
      for (int i4 = t; i4 < NV / 4; i4 += 1024) {
        float4 e4 = *(const float4*)(e + i4 * 4);
        unsigned k;
        k = __float_as_uint(e4.x); if (k && (k >> ms) == pfx) HACC(e4.x, (k >> bsh) & 1023u);
        k = __float_as_uint(e4.y); if (k && (k >> ms) == pfx) HACC(e4.y, (k >> bsh) & 1023u);
        k = __float_as_uint(e4.z); if (k && (k >> ms) == pfx) HACC(e4.z, (k >> bsh) & 1023u);
        k = __float_as_uint(e4.w); if (k && (k >> ms) == pfx) HACC(e4.w, (k >> bsh) & 1023u);
      }
      __syncthreads();
    }
  }
#undef HACC

  // ---- final filter ----
  const unsigned ustar = sp.ustar;
  const float invZ = sp.invZ;
  if (sp.m >= sp.cEq) {
    for (int i4 = t; i4 < NV / 4; i4 += 1024) {
      float4 e4 = *(const float4*)(e + i4 * 4);
      float4 o4;
      unsigned k;
      k = __float_as_uint(e4.x); o4.x = (k >= ustar) ? e4.x * invZ : 0.f;
      k = __float_as_uint(e4.y); o4.y = (k >= ustar) ? e4.y * invZ : 0.f;
      k = __float_as_uint(e4.z); o4.z = (k >= ustar) ? e4.z * invZ : 0.f;
      k = __float_as_uint(e4.w); o4.w = (k >= ustar) ? e4.w * invZ : 0.f;
      *(float4*)(row + i4 * 4) = o4;
    }
  } else {
    // rare: rank ties by vocab index, keep first m
    const int m = sp.m;
    unsigned* rk = hist;  // 1024 u32, suf dead now
    const int base0 = t * 32;
    const int end0 = (base0 + 32 < NV) ? base0 + 32 : NV;
    int myc = 0;
    for (int v = base0; v < end0; v++)
      myc += (__float_as_uint(e[v]) == ustar);
    rk[t] = (unsigned)myc;
    __syncthreads();
    for (int off = 1; off < 1024; off <<= 1) {
      const unsigned a0 = rk[t];
      const unsigned an = (t >= off) ? rk[t - off] : 0u;
      __syncthreads();
      rk[t] = a0 + an;
      __syncthreads();
    }
    int r = (t > 0) ? (int)rk[t - 1] : 0;
    for (int v = base0; v < end0; v++) {
      const unsigned k = __float_as_uint(e[v]);
      float o = (k > ustar) ? e[v] * invZ : 0.f;
      if (k == ustar) { o = (r < m) ? e[v] * invZ : 0.f; r++; }
      row[v] = o;
    }
  }
}

extern "C" void kernel_launch(void* const* d_in, const int* in_sizes, int n_in,
                              void* d_out, int out_size, void* d_ws, size_t ws_size,
                              hipStream_t stream) {
  (void)in_sizes; (void)n_in; (void)out_size; (void)ws_size;
  const float* hidden = (const float*)d_in[0];
  const float* emb    = (const float*)d_in[1];
  const int*   toks   = (const int*)d_in[2];
  const float* pres   = (const float*)d_in[3];
  const float* freq   = (const float*)d_in[4];
  const float* temp   = (const float*)d_in[5];
  const float* topp   = (const float*)d_in[6];
  const int*   topk   = (const int*)d_in[7];
  float* out = (float*)d_out;

  // ws layout: A3 (1,835,008 B) + rowmax (1,024 B, zeroed)
  const size_t offA3 = 0;
  const size_t offRM = 1835008;

  _Float16* A3 = (_Float16*)((char*)d_ws + offA3);
  unsigned* rowmax = (unsigned*)((char*)d_ws + offRM);

  hipFuncSetAttribute((const void*)sample_row,
                      hipFuncAttributeMaxDynamicSharedMemorySize, SMEM_BYTES);

  hipMemsetAsync((char*)d_ws + offRM, 0, 1024, stream);
  convert_A<<<NKB, 256, 0, stream>>>(hidden, A3);
  gemm_f16s<<<NGBLK, 256, 0, stream>>>(emb, A3, temp, rowmax, out);
  sample_row<<<NB, 1024, SMEM_BYTES, stream>>>(out, rowmax, toks, pres, freq,
                                               temp, topp, topk);
}